// Round 1
// baseline (546.810 us; speedup 1.0000x reference)
//
#include <hip/hip_runtime.h>
#include <hip/hip_bf16.h>

// Problem geometry (all compile-time):
//  image 2048x2048 f32 -> conv2x2 stride2 'SAME' (=valid here) -> hi 1024x1024
//  pad to 1449x1449 with hi at offset (212,212), center=724
//  out grid 1448x1448, 64 angles (theta = 0..63 radians)
//  A[x][a] = sum_y bilinear_wrap(padded, rot(x,y,a)) ; out = A / max(A)

#define HM 1024            // hi dim
#define PW 1449            // padded dim
#define PAD0 212
#define OW 1448
#define NA 64
#define NOUT (OW * NA)     // 92672
#define CENTER 724.0f

__global__ __launch_bounds__(256) void k_dwt(const float* __restrict__ img,
                                             float* __restrict__ hi) {
    int gid = blockIdx.x * blockDim.x + threadIdx.x;
    if (gid >= HM * HM) return;
    int i = gid >> 10;
    int j = gid & 1023;
    const float2* r0 = reinterpret_cast<const float2*>(img + (size_t)(2 * i) * 2048);
    const float2* r1 = reinterpret_cast<const float2*>(img + (size_t)(2 * i + 1) * 2048);
    float2 a = r0[j];
    float2 b = r1[j];
    hi[gid] = fmaf(-0.1384f, a.x,
              fmaf( 0.7243f, a.y,
              fmaf(-0.6038f, b.x, 0.1601f * b.y)));
}

template <int YS>
__global__ __launch_bounds__(256) void k_proj(const float* __restrict__ hi,
                                              float* __restrict__ partial) {
    int gid = blockIdx.x * blockDim.x + threadIdx.x;
    if (gid >= NA * OW * YS) return;
    int x    = gid % OW;          // lanes consecutive in x -> gather locality
    int rest = gid / OW;
    int a    = rest & (NA - 1);
    int chunk = rest >> 6;

    float fa = (float)a;
    float c = cosf(fa);
    float s = sinf(fa);
    float bx = -CENTER * (c + s - 1.0f);
    float by = -CENTER * (c - s - 1.0f);
    float cx = fmaf(c, (float)x, bx);   // x_in = cx + s*y
    float cy = fmaf(-s, (float)x, by);  // y_in = cy + c*y

    const int ylen = OW / YS;           // 1448/8 = 181
    int ybeg = chunk * ylen;
    int yend = ybeg + ylen;

    float acc = 0.0f;
    for (int y = ybeg; y < yend; ++y) {
        float x_in = fmaf(s, (float)y, cx);
        float y_in = fmaf(c, (float)y, cy);
        float fx0 = floorf(x_in);
        float fy0 = floorf(y_in);
        float dx = x_in - fx0;
        float dy = y_in - fy0;
        int ix = (int)fx0;
        int iy = (int)fy0;
        int x0 = ix % PW; if (x0 < 0) x0 += PW;
        int y0 = iy % PW; if (y0 < 0) y0 += PW;
        int x1 = x0 + 1; if (x1 == PW) x1 = 0;
        int y1 = y0 + 1; if (y1 == PW) y1 = 0;
        // map padded coords -> hi coords with implicit zero border
        int hx0 = x0 - PAD0, hx1 = x1 - PAD0;
        int hy0 = y0 - PAD0, hy1 = y1 - PAD0;
        bool inx0 = (unsigned)hx0 < (unsigned)HM;
        bool inx1 = (unsigned)hx1 < (unsigned)HM;
        bool iny0 = (unsigned)hy0 < (unsigned)HM;
        bool iny1 = (unsigned)hy1 < (unsigned)HM;
        float v00 = (inx0 && iny0) ? hi[hy0 * HM + hx0] : 0.0f;
        float v01 = (inx1 && iny0) ? hi[hy0 * HM + hx1] : 0.0f;
        float v10 = (inx0 && iny1) ? hi[hy1 * HM + hx0] : 0.0f;
        float v11 = (inx1 && iny1) ? hi[hy1 * HM + hx1] : 0.0f;
        float omdx = 1.0f - dx;
        float omdy = 1.0f - dy;
        float w00 = omdy * omdx;
        float w01 = omdy * dx;
        float w10 = dy * omdx;
        float w11 = dy * dx;
        acc += fmaf(v00, w00, fmaf(v01, w01, fmaf(v10, w10, v11 * w11)));
    }
    // layout: partial[chunk][a*OW + x]  (coalesced store)
    partial[(size_t)chunk * NOUT + a * OW + x] = acc;
}

template <int YS>
__global__ __launch_bounds__(256) void k_combine(const float* __restrict__ partial,
                                                 float* __restrict__ out) {
    int gid = blockIdx.x * blockDim.x + threadIdx.x;
    if (gid >= NOUT) return;
    float sum = 0.0f;
#pragma unroll
    for (int cth = 0; cth < YS; ++cth) sum += partial[(size_t)cth * NOUT + gid];
    int a = gid / OW;
    int x = gid % OW;
    out[x * NA + a] = sum;   // transpose: A = lines.T
}

__global__ __launch_bounds__(256) void k_max(const float* __restrict__ out,
                                             float* __restrict__ mx) {
    __shared__ float sm[4];
    float m = -3.4e38f;
    for (int i = threadIdx.x; i < NOUT; i += 256) m = fmaxf(m, out[i]);
#pragma unroll
    for (int off = 32; off > 0; off >>= 1) m = fmaxf(m, __shfl_down(m, off, 64));
    int lane = threadIdx.x & 63;
    int w = threadIdx.x >> 6;
    if (lane == 0) sm[w] = m;
    __syncthreads();
    if (threadIdx.x == 0) {
        float r = fmaxf(fmaxf(sm[0], sm[1]), fmaxf(sm[2], sm[3]));
        *mx = r;
    }
}

__global__ __launch_bounds__(256) void k_norm(float* __restrict__ out,
                                              const float* __restrict__ mx) {
    int gid = blockIdx.x * blockDim.x + threadIdx.x;
    if (gid < NOUT) out[gid] = out[gid] / (*mx);
}

extern "C" void kernel_launch(void* const* d_in, const int* in_sizes, int n_in,
                              void* d_out, int out_size, void* d_ws, size_t ws_size,
                              hipStream_t stream) {
    const float* img = (const float*)d_in[0];
    float* out = (float*)d_out;

    float* hi = (float*)d_ws;                       // 1024*1024 floats = 4 MiB
    float* partial = hi + (size_t)HM * HM;

    k_dwt<<<(HM * HM + 255) / 256, 256, 0, stream>>>(img, hi);

    const size_t need8 = (size_t)HM * HM * 4 + (size_t)8 * NOUT * 4 + 4;
    if (ws_size >= need8) {
        constexpr int YS = 8;
        float* mx = partial + (size_t)YS * NOUT;
        k_proj<YS><<<(NA * OW * YS + 255) / 256, 256, 0, stream>>>(hi, partial);
        k_combine<YS><<<(NOUT + 255) / 256, 256, 0, stream>>>(partial, out);
        k_max<<<1, 256, 0, stream>>>(out, mx);
        k_norm<<<(NOUT + 255) / 256, 256, 0, stream>>>(out, mx);
    } else {
        constexpr int YS = 1;
        float* mx = partial + (size_t)YS * NOUT;
        k_proj<YS><<<(NA * OW * YS + 255) / 256, 256, 0, stream>>>(hi, partial);
        k_combine<YS><<<(NOUT + 255) / 256, 256, 0, stream>>>(partial, out);
        k_max<<<1, 256, 0, stream>>>(out, mx);
        k_norm<<<(NOUT + 255) / 256, 256, 0, stream>>>(out, mx);
    }
}

// Round 2
// 280.752 us; speedup vs baseline: 1.9477x; 1.9477x over previous
//
#include <hip/hip_runtime.h>
#include <hip/hip_bf16.h>

// Geometry (compile-time):
//  image 2048x2048 f32 -> conv2x2 stride2 -> hi 1024x1024
//  pad to 1449x1449, hi at offset (212,212), center=724
//  out grid 1448x1448, 64 angles (theta = 0..63 radians)
//  A[x][a] = sum_y bilinear_wrap(padded, rot(x,y,a)) ; out = A / max(A)

#define HM 1024
#define PW 1449
#define PAD0 212
#define OW 1448
#define NA 64
#define NOUT (OW * NA)     // 92672
#define CENTER 724.0f
#define XS_N 181           // 1448/8 x-strips
#define YS 4               // y chunks
#define NWAVES (XS_N * NA * YS)   // 46336
#define NBLOCKS (NWAVES / 4)      // 11584

__global__ __launch_bounds__(256) void k_dwt(const float* __restrict__ img,
                                             float* __restrict__ hi) {
    int gid = blockIdx.x * blockDim.x + threadIdx.x;
    if (gid >= HM * HM) return;
    int i = gid >> 10;
    int j = gid & 1023;
    const float2* r0 = reinterpret_cast<const float2*>(img + (size_t)(2 * i) * 2048);
    const float2* r1 = reinterpret_cast<const float2*>(img + (size_t)(2 * i + 1) * 2048);
    float2 a = r0[j];
    float2 b = r1[j];
    hi[gid] = fmaf(-0.1384f, a.x,
              fmaf( 0.7243f, a.y,
              fmaf(-0.6038f, b.x, 0.1601f * b.y)));
}

// Each wave: one angle, one 8-wide x-strip, one y-chunk. Lane = (ly=lane>>3,
// lx=lane&7). Wave footprint per iteration = rotated 8x8 patch -> ~12-16
// cache lines per gather (vs ~40 for a 64x1 line).
__global__ __launch_bounds__(256) void k_proj(const float* __restrict__ hi,
                                              float* __restrict__ partial) {
    int wave_id = blockIdx.x * 4 + (threadIdx.x >> 6);
    int lane = threadIdx.x & 63;
    int lx = lane & 7;
    int ly = lane >> 3;

    int xs = wave_id % XS_N;
    int t  = wave_id / XS_N;
    int a  = t & (NA - 1);
    int chunk = t >> 6;

    int X = xs * 8 + lx;

    float fa = (float)a;
    float c = cosf(fa);
    float s = sinf(fa);
    float bx = -CENTER * (c + s - 1.0f);
    float by = -CENTER * (c - s - 1.0f);
    float cx = fmaf(c, (float)X, bx);    // x_in = cx + s*Y
    float cy = fmaf(-s, (float)X, by);   // y_in = cy + c*Y

    int oct_beg = (chunk * XS_N) / YS;
    int oct_end = ((chunk + 1) * XS_N) / YS;

    float yf = (float)(oct_beg * 8 + ly);
    float acc = 0.0f;
    for (int oct = oct_beg; oct < oct_end; ++oct, yf += 8.0f) {
        float x_in = fmaf(s, yf, cx);
        float y_in = fmaf(c, yf, cy);
        float fx0 = floorf(x_in);
        float fy0 = floorf(y_in);
        float dx = x_in - fx0;
        float dy = y_in - fy0;
        int ix = (int)fx0;
        int iy = (int)fy0;
        int x0 = ix % PW; if (x0 < 0) x0 += PW;
        int y0 = iy % PW; if (y0 < 0) y0 += PW;
        int x1 = x0 + 1; if (x1 == PW) x1 = 0;
        int y1 = y0 + 1; if (y1 == PW) y1 = 0;
        int hx0 = x0 - PAD0, hx1 = x1 - PAD0;
        int hy0 = y0 - PAD0, hy1 = y1 - PAD0;
        bool inx0 = (unsigned)hx0 < (unsigned)HM;
        bool inx1 = (unsigned)hx1 < (unsigned)HM;
        bool iny0 = (unsigned)hy0 < (unsigned)HM;
        bool iny1 = (unsigned)hy1 < (unsigned)HM;
        float v00 = (inx0 && iny0) ? hi[hy0 * HM + hx0] : 0.0f;
        float v01 = (inx1 && iny0) ? hi[hy0 * HM + hx1] : 0.0f;
        float v10 = (inx0 && iny1) ? hi[hy1 * HM + hx0] : 0.0f;
        float v11 = (inx1 && iny1) ? hi[hy1 * HM + hx1] : 0.0f;
        float omdx = 1.0f - dx;
        float omdy = 1.0f - dy;
        float w00 = omdy * omdx;
        float w01 = omdy * dx;
        float w10 = dy * omdx;
        float w11 = dy * dx;
        acc += fmaf(v00, w00, fmaf(v01, w01, fmaf(v10, w10, v11 * w11)));
    }

    // reduce over ly (lanes differing in bits 3,4,5)
    acc += __shfl_xor(acc, 8, 64);
    acc += __shfl_xor(acc, 16, 64);
    acc += __shfl_xor(acc, 32, 64);

    if (ly == 0) partial[(size_t)chunk * NOUT + a * OW + X] = acc;
}

template <int NCH>
__global__ __launch_bounds__(256) void k_combine(const float* __restrict__ partial,
                                                 float* __restrict__ out) {
    int gid = blockIdx.x * blockDim.x + threadIdx.x;
    if (gid >= NOUT) return;
    float sum = 0.0f;
#pragma unroll
    for (int cth = 0; cth < NCH; ++cth) sum += partial[(size_t)cth * NOUT + gid];
    int a = gid / OW;
    int x = gid % OW;
    out[x * NA + a] = sum;   // transpose: A = lines.T
}

__global__ __launch_bounds__(256) void k_max1(const float* __restrict__ out,
                                              float* __restrict__ bmax) {
    __shared__ float sm[4];
    const float4* o4 = reinterpret_cast<const float4*>(out);
    const int n4 = NOUT / 4;  // 23168
    float m = -3.4e38f;
    for (int i = blockIdx.x * 256 + threadIdx.x; i < n4; i += gridDim.x * 256) {
        float4 v = o4[i];
        m = fmaxf(fmaxf(fmaxf(m, v.x), fmaxf(v.y, v.z)), v.w);
    }
#pragma unroll
    for (int off = 32; off > 0; off >>= 1) m = fmaxf(m, __shfl_down(m, off, 64));
    int lane = threadIdx.x & 63;
    int w = threadIdx.x >> 6;
    if (lane == 0) sm[w] = m;
    __syncthreads();
    if (threadIdx.x == 0)
        bmax[blockIdx.x] = fmaxf(fmaxf(sm[0], sm[1]), fmaxf(sm[2], sm[3]));
}

__global__ __launch_bounds__(64) void k_max2(const float* __restrict__ bmax,
                                             float* __restrict__ mx) {
    float m = bmax[threadIdx.x];
#pragma unroll
    for (int off = 32; off > 0; off >>= 1) m = fmaxf(m, __shfl_down(m, off, 64));
    if (threadIdx.x == 0) *mx = m;
}

__global__ __launch_bounds__(256) void k_norm(float* __restrict__ out,
                                              const float* __restrict__ mx) {
    int gid = blockIdx.x * blockDim.x + threadIdx.x;
    if (gid < NOUT) out[gid] = out[gid] / (*mx);
}

extern "C" void kernel_launch(void* const* d_in, const int* in_sizes, int n_in,
                              void* d_out, int out_size, void* d_ws, size_t ws_size,
                              hipStream_t stream) {
    const float* img = (const float*)d_in[0];
    float* out = (float*)d_out;

    float* hi = (float*)d_ws;                       // 4 MiB
    float* partial = hi + (size_t)HM * HM;

    k_dwt<<<(HM * HM + 255) / 256, 256, 0, stream>>>(img, hi);

    const size_t need4 = (size_t)HM * HM * 4 + (size_t)YS * NOUT * 4 + 65 * 4;
    if (ws_size >= need4) {
        float* bmax = partial + (size_t)YS * NOUT;   // 64 floats
        float* mx = bmax + 64;
        k_proj<<<NBLOCKS, 256, 0, stream>>>(hi, partial);
        k_combine<YS><<<(NOUT + 255) / 256, 256, 0, stream>>>(partial, out);
        k_max1<<<64, 256, 0, stream>>>(out, bmax);
        k_max2<<<1, 64, 0, stream>>>(bmax, mx);
        k_norm<<<(NOUT + 255) / 256, 256, 0, stream>>>(out, mx);
    }
}

// Round 3
// 154.167 us; speedup vs baseline: 3.5469x; 1.8211x over previous
//
#include <hip/hip_runtime.h>
#include <hip/hip_bf16.h>

// Geometry (compile-time):
//  image 2048x2048 f32 -> conv2x2 stride2 -> hi 1024x1024
//  padded 1449x1449, hi at offset (212,212), center=724
//  out grid 1448x1448, 64 angles (theta = 0..63 radians)
//  A[x][a] = sum_y bilinear_wrap(padded, rot(x,y,a)) ; out = A / max(A)

#define HM 1024
#define PW 1449
#define PAD0 212
#define OW 1448
#define NA 64
#define NOUT (OW * NA)     // 92672
#define CENTER 724.0f
#define XS_N 181           // 1448/8 x-strips
#define YS 4               // y chunks
#define NWAVES (XS_N * NA * YS)   // 46336
#define NBLOCKS (NWAVES / 4)      // 11584

// ---------- fast path: fused conv + zero-pad into P[1449*1449] ----------
__global__ __launch_bounds__(256) void k_pad_dwt(const float* __restrict__ img,
                                                 float* __restrict__ P) {
    int gid = blockIdx.x * blockDim.x + threadIdx.x;
    if (gid >= PW * PW) return;
    int r = gid / PW;
    int cidx = gid - r * PW;
    int i = r - PAD0;
    int j = cidx - PAD0;
    float v = 0.0f;
    if ((unsigned)i < (unsigned)HM && (unsigned)j < (unsigned)HM) {
        const float2* r0 = reinterpret_cast<const float2*>(img + (size_t)(2 * i) * 2048);
        const float2* r1 = reinterpret_cast<const float2*>(img + (size_t)(2 * i + 1) * 2048);
        float2 a = r0[j];
        float2 b = r1[j];
        v = fmaf(-0.1384f, a.x,
            fmaf( 0.7243f, a.y,
            fmaf(-0.6038f, b.x, 0.1601f * b.y)));
    }
    P[gid] = v;
}

// Wave = (angle, 8-wide x-strip, y-chunk); lane = (ly=lane>>3, lx=lane&7).
// Coords pre-shifted by +1449 so floor-result is in [424,3922); mod 1449 via
// exact magic-mul; all-pad samples (48%) skipped by one range test.
__global__ __launch_bounds__(256) void k_proj_pad(const float* __restrict__ P,
                                                  float* __restrict__ partial) {
    int wave_id = blockIdx.x * 4 + (threadIdx.x >> 6);
    int lane = threadIdx.x & 63;
    int lx = lane & 7;
    int ly = lane >> 3;

    int xs = wave_id % XS_N;
    int t  = wave_id / XS_N;
    int a  = t & (NA - 1);
    int chunk = t >> 6;

    int X = xs * 8 + lx;

    float fa = (float)a;
    float c = cosf(fa);
    float s = sinf(fa);
    float bx = -CENTER * (c + s - 1.0f);
    float by = -CENTER * (c - s - 1.0f);
    float cxs = fmaf(c, (float)X, bx) + (float)PW;   // x_s = cxs + s*Y
    float cys = fmaf(-s, (float)X, by) + (float)PW;  // y_s = cys + c*Y

    int oct_beg = (chunk * XS_N) / YS;
    int oct_end = ((chunk + 1) * XS_N) / YS;

    float yf = (float)(oct_beg * 8 + ly);
    float acc = 0.0f;
    for (int oct = oct_beg; oct < oct_end; ++oct, yf += 8.0f) {
        float x_s = fmaf(s, yf, cxs);
        float y_s = fmaf(c, yf, cys);
        float fx = floorf(x_s);
        float fy = floorf(y_s);
        float dx = x_s - fx;
        float dy = y_s - fy;
        unsigned ux = (unsigned)fx;                     // [424, 3922)
        unsigned uy = (unsigned)fy;
        int x0 = (int)(ux - ((ux * 11581u) >> 24) * 1449u);  // exact mod 1449
        int y0 = (int)(uy - ((uy * 11581u) >> 24) * 1449u);
        unsigned hx = (unsigned)(x0 - (PAD0 - 1));
        unsigned hy = (unsigned)(y0 - (PAD0 - 1));
        if (hx <= 1024u && hy <= 1024u) {
            const float* p0 = P + (y0 * PW + x0);
            float v00 = p0[0];
            float v01 = p0[1];
            float v10 = p0[PW];
            float v11 = p0[PW + 1];
            float top = fmaf(dx, v01 - v00, v00);
            float bot = fmaf(dx, v11 - v10, v10);
            acc = fmaf(dy, bot - top, acc + top);
        }
    }

    acc += __shfl_xor(acc, 8, 64);
    acc += __shfl_xor(acc, 16, 64);
    acc += __shfl_xor(acc, 32, 64);

    if (ly == 0) partial[(size_t)chunk * NOUT + a * OW + X] = acc;
}

// ---------- fallback path (round-2 proven): hi[1024^2], masked gathers ----
__global__ __launch_bounds__(256) void k_dwt(const float* __restrict__ img,
                                             float* __restrict__ hi) {
    int gid = blockIdx.x * blockDim.x + threadIdx.x;
    if (gid >= HM * HM) return;
    int i = gid >> 10;
    int j = gid & 1023;
    const float2* r0 = reinterpret_cast<const float2*>(img + (size_t)(2 * i) * 2048);
    const float2* r1 = reinterpret_cast<const float2*>(img + (size_t)(2 * i + 1) * 2048);
    float2 a = r0[j];
    float2 b = r1[j];
    hi[gid] = fmaf(-0.1384f, a.x,
              fmaf( 0.7243f, a.y,
              fmaf(-0.6038f, b.x, 0.1601f * b.y)));
}

__global__ __launch_bounds__(256) void k_proj_nopad(const float* __restrict__ hi,
                                                    float* __restrict__ partial) {
    int wave_id = blockIdx.x * 4 + (threadIdx.x >> 6);
    int lane = threadIdx.x & 63;
    int lx = lane & 7;
    int ly = lane >> 3;

    int xs = wave_id % XS_N;
    int t  = wave_id / XS_N;
    int a  = t & (NA - 1);
    int chunk = t >> 6;

    int X = xs * 8 + lx;

    float fa = (float)a;
    float c = cosf(fa);
    float s = sinf(fa);
    float bx = -CENTER * (c + s - 1.0f);
    float by = -CENTER * (c - s - 1.0f);
    float cx = fmaf(c, (float)X, bx);
    float cy = fmaf(-s, (float)X, by);

    int oct_beg = (chunk * XS_N) / YS;
    int oct_end = ((chunk + 1) * XS_N) / YS;

    float yf = (float)(oct_beg * 8 + ly);
    float acc = 0.0f;
    for (int oct = oct_beg; oct < oct_end; ++oct, yf += 8.0f) {
        float x_in = fmaf(s, yf, cx);
        float y_in = fmaf(c, yf, cy);
        float fx0 = floorf(x_in);
        float fy0 = floorf(y_in);
        float dx = x_in - fx0;
        float dy = y_in - fy0;
        int ix = (int)fx0;
        int iy = (int)fy0;
        int x0 = ix % PW; if (x0 < 0) x0 += PW;
        int y0 = iy % PW; if (y0 < 0) y0 += PW;
        int x1 = x0 + 1; if (x1 == PW) x1 = 0;
        int y1 = y0 + 1; if (y1 == PW) y1 = 0;
        int hx0 = x0 - PAD0, hx1 = x1 - PAD0;
        int hy0 = y0 - PAD0, hy1 = y1 - PAD0;
        bool inx0 = (unsigned)hx0 < (unsigned)HM;
        bool inx1 = (unsigned)hx1 < (unsigned)HM;
        bool iny0 = (unsigned)hy0 < (unsigned)HM;
        bool iny1 = (unsigned)hy1 < (unsigned)HM;
        float v00 = (inx0 && iny0) ? hi[hy0 * HM + hx0] : 0.0f;
        float v01 = (inx1 && iny0) ? hi[hy0 * HM + hx1] : 0.0f;
        float v10 = (inx0 && iny1) ? hi[hy1 * HM + hx0] : 0.0f;
        float v11 = (inx1 && iny1) ? hi[hy1 * HM + hx1] : 0.0f;
        float omdx = 1.0f - dx;
        float omdy = 1.0f - dy;
        acc += fmaf(v00, omdy * omdx, fmaf(v01, omdy * dx,
               fmaf(v10, dy * omdx, v11 * (dy * dx))));
    }

    acc += __shfl_xor(acc, 8, 64);
    acc += __shfl_xor(acc, 16, 64);
    acc += __shfl_xor(acc, 32, 64);

    if (ly == 0) partial[(size_t)chunk * NOUT + a * OW + X] = acc;
}

// ---------- shared epilogue ----------
template <int NCH>
__global__ __launch_bounds__(256) void k_combine(const float* __restrict__ partial,
                                                 float* __restrict__ out) {
    int gid = blockIdx.x * blockDim.x + threadIdx.x;
    if (gid >= NOUT) return;
    float sum = 0.0f;
#pragma unroll
    for (int cth = 0; cth < NCH; ++cth) sum += partial[(size_t)cth * NOUT + gid];
    int a = gid / OW;
    int x = gid % OW;
    out[x * NA + a] = sum;   // transpose: A = lines.T
}

__global__ __launch_bounds__(256) void k_max1(const float* __restrict__ out,
                                              float* __restrict__ bmax) {
    __shared__ float sm[4];
    const float4* o4 = reinterpret_cast<const float4*>(out);
    const int n4 = NOUT / 4;
    float m = -3.4e38f;
    for (int i = blockIdx.x * 256 + threadIdx.x; i < n4; i += gridDim.x * 256) {
        float4 v = o4[i];
        m = fmaxf(fmaxf(fmaxf(m, v.x), fmaxf(v.y, v.z)), v.w);
    }
#pragma unroll
    for (int off = 32; off > 0; off >>= 1) m = fmaxf(m, __shfl_down(m, off, 64));
    int lane = threadIdx.x & 63;
    int w = threadIdx.x >> 6;
    if (lane == 0) sm[w] = m;
    __syncthreads();
    if (threadIdx.x == 0)
        bmax[blockIdx.x] = fmaxf(fmaxf(sm[0], sm[1]), fmaxf(sm[2], sm[3]));
}

__global__ __launch_bounds__(64) void k_max2(const float* __restrict__ bmax,
                                             float* __restrict__ mx) {
    float m = bmax[threadIdx.x];
#pragma unroll
    for (int off = 32; off > 0; off >>= 1) m = fmaxf(m, __shfl_down(m, off, 64));
    if (threadIdx.x == 0) *mx = m;
}

__global__ __launch_bounds__(256) void k_norm(float* __restrict__ out,
                                              const float* __restrict__ mx) {
    int gid = blockIdx.x * blockDim.x + threadIdx.x;
    if (gid < NOUT) out[gid] = out[gid] / (*mx);
}

extern "C" void kernel_launch(void* const* d_in, const int* in_sizes, int n_in,
                              void* d_out, int out_size, void* d_ws, size_t ws_size,
                              hipStream_t stream) {
    const float* img = (const float*)d_in[0];
    float* out = (float*)d_out;

    const size_t npad = (size_t)PW * PW;                 // 2,099,601 floats
    const size_t need_pad = (npad + (size_t)YS * NOUT + 65) * 4;
    const size_t need_old = ((size_t)HM * HM + (size_t)YS * NOUT + 65) * 4;

    if (ws_size >= need_pad) {
        float* P = (float*)d_ws;
        float* partial = P + npad;
        float* bmax = partial + (size_t)YS * NOUT;
        float* mx = bmax + 64;
        k_pad_dwt<<<(int)((npad + 255) / 256), 256, 0, stream>>>(img, P);
        k_proj_pad<<<NBLOCKS, 256, 0, stream>>>(P, partial);
        k_combine<YS><<<(NOUT + 255) / 256, 256, 0, stream>>>(partial, out);
        k_max1<<<64, 256, 0, stream>>>(out, bmax);
        k_max2<<<1, 64, 0, stream>>>(bmax, mx);
        k_norm<<<(NOUT + 255) / 256, 256, 0, stream>>>(out, mx);
    } else if (ws_size >= need_old) {
        float* hi = (float*)d_ws;
        float* partial = hi + (size_t)HM * HM;
        float* bmax = partial + (size_t)YS * NOUT;
        float* mx = bmax + 64;
        k_dwt<<<(HM * HM + 255) / 256, 256, 0, stream>>>(img, hi);
        k_proj_nopad<<<NBLOCKS, 256, 0, stream>>>(hi, partial);
        k_combine<YS><<<(NOUT + 255) / 256, 256, 0, stream>>>(partial, out);
        k_max1<<<64, 256, 0, stream>>>(out, bmax);
        k_max2<<<1, 64, 0, stream>>>(bmax, mx);
        k_norm<<<(NOUT + 255) / 256, 256, 0, stream>>>(out, mx);
    }
}